// Round 11
// baseline (192.580 us; speedup 1.0000x reference)
//
#include <hip/hip_runtime.h>
#include <stdint.h>

typedef int i32x4 __attribute__((ext_vector_type(4)));
typedef float f32x4 __attribute__((ext_vector_type(4)));

#define N_IMG 32
#define C_IN 256
#define H_IN 56
#define W_IN 56
#define K_OUT 256
#define H_OUT 54
#define W_OUT 54
#define HW_OUT 2916          // 54*54
#define M_PIX 93312          // 32*2916 = 128 * 729
#define CHW_OUT 746496       // 256*2916

#define BM 128               // pixel rows per block (grid 729)
#define HALO_ROWS 368        // max needed row = ~359 (incl image-crossing)

#define XT_BYTES ((size_t)N_IMG * H_IN * W_IN * C_IN)   // 25,690,112 (i8 NHWC)
#define WT_BYTES ((size_t)9 * K_OUT * C_IN)             // 589,824

// -------- transforms --------
// xt: NCHW i32 -> NHWC i8 (clip 0..7)
// wt: OIHW f32 -> [tap][h][kk][o][g]x16B: one B-fragment = wave-contiguous 1KB.
//     (tap,h) stride 32768, kk stride 16384, o stride 64, g stride 16.
__global__ __launch_bounds__(256) void xform(const int* __restrict__ x,
                                             const float* __restrict__ w,
                                             unsigned char* __restrict__ xt,
                                             unsigned char* __restrict__ wt) {
    const int bid = blockIdx.x;
    if (bid < N_IMG * H_IN) {
        const int n = bid / H_IN;
        const int h = bid % H_IN;
        const int c = threadIdx.x;
        const int* src = x + ((size_t)((n * C_IN + c) * H_IN + h)) * W_IN;
        unsigned char* dst = xt + ((size_t)(n * H_IN + h) * W_IN) * C_IN + c;
        #pragma unroll
        for (int w0 = 0; w0 < W_IN; w0 += 4) {
            int4 v = *(const int4*)(src + w0);
            int a[4] = {v.x, v.y, v.z, v.w};
            #pragma unroll
            for (int j = 0; j < 4; ++j) {
                int q = a[j] < 0 ? 0 : (a[j] > 7 ? 7 : a[j]);
                dst[(size_t)(w0 + j) * C_IN] = (unsigned char)q;
            }
        }
    } else {
        const int o = bid - N_IMG * H_IN;     // out-channel
        const int c = threadIdx.x;            // in-channel
        const float* src = w + ((size_t)o * C_IN + c) * 9;
        const int h  = c >> 7;                // 128-half
        const int kk = (c >> 6) & 1;          // 64 within half
        const int g  = (c >> 4) & 3;          // 16-chunk within 64
        const int b  = c & 15;                // byte within 16
        #pragma unroll
        for (int rs = 0; rs < 9; ++rs) {
            int iv = (int)src[rs];   // truncation == astype(int32); values 0..6
            wt[(size_t)((rs * 2 + h) * 2 + kk) * 16384 + o * 64 + g * 16 + b]
                = (unsigned char)iv;
        }
    }
}

// -------- async global->LDS (width 16) --------
__device__ __forceinline__ void gload_lds16(const void* g, void* l) {
    __builtin_amdgcn_global_load_lds(
        (const __attribute__((address_space(1))) uint32_t*)g,
        (__attribute__((address_space(3))) uint32_t*)l,
        16, 0, 0);
}

// -------- main conv (i8): occupancy-first, barrier-free K-loop --------
// BM=128 pix x BN=256 ch; 8 waves (2M x 4N), per-wave 64x64, acc[4][4]=64 AGPR.
// Total regs <=128 (launch_bounds(512,4)) -> 4 waves/SIMD; LDS = halo only
// (47KB) -> 2 blocks/CU. TLP (16 waves/CU) hides LDS + L2 latency.
__global__ __launch_bounds__(512, 4) void conv_mfma(const unsigned char* __restrict__ xt,
                                                    const unsigned char* __restrict__ wt,
                                                    float* __restrict__ out) {
    __shared__ __align__(16) unsigned char halo[HALO_ROWS * 128];   // 47104 B

    const int t512 = threadIdx.x;
    const int l    = t512 & 63;
    const int wid  = t512 >> 6;
    const int wr   = wid >> 2;     // 0..1 -> 64-pixel half
    const int wc   = wid & 3;      // 0..3 -> 64-channel quarter
    const int mb   = blockIdx.x;   // 729 M-tiles

    // halo staging geometry (proven both-sides swizzle): 8KB rounds of 64 rows
    const int slot = t512 & 7;
    const int srow = t512 >> 3;
    const int cs   = ((slot ^ (srow & 7)) << 4);
    const int tb16 = t512 * 16;
    const int sb   = srow * 256 + cs;

    // block-base input pixel
    const int m0  = mb * BM;
    const int n0  = m0 / HW_OUT;
    const int rm0 = m0 - n0 * HW_OUT;
    const int oh0 = rm0 / W_OUT;
    const int ow0 = rm0 - oh0 * W_OUT;
    const int pix0 = n0 * (H_IN * W_IN) + oh0 * W_IN + ow0;

    // per-lane halo row deltas for the 4 M-fragments (exact mapping, <=~359)
    const int lrow = l & 15;
    int drow[4];
    #pragma unroll
    for (int mf = 0; mf < 4; ++mf) {
        const int m   = m0 + wr * 64 + mf * 16 + lrow;
        const int n   = m / HW_OUT;
        const int rem = m - n * HW_OUT;
        const int oh  = rem / W_OUT;
        const int ow  = rem - oh * W_OUT;
        drow[mf] = n * (H_IN * W_IN) + oh * W_IN + ow - pix0;
    }

    const unsigned g16 = (unsigned)((l >> 4) << 4);   // 0/16/32/48

    // B fragment base: layout [tap][h][kk][o][g]x16B (R9-verified strides)
    const char* wb = (const char*)wt;
    const char* bptr[4];
    #pragma unroll
    for (int nf = 0; nf < 4; ++nf)
        bptr[nf] = wb + (wc * 64 + nf * 16 + (l & 15)) * 64 + (l >> 4) * 16;

    i32x4 acc[4][4];
    #pragma unroll
    for (int i = 0; i < 4; ++i)
        #pragma unroll
        for (int j = 0; j < 4; ++j)
            acc[i][j] = (i32x4){0, 0, 0, 0};

    const char* xb = (const char*)xt;

    // halo: 5 full 8KB rounds (rows 0..319) + partial round (rows 320..367)
    #define STAGE_HALO(H) do {                                               \
        const char* hs_ = xb + (size_t)pix0 * 256 + (H) * 128 + sb;          \
        _Pragma("unroll")                                                    \
        for (int i_ = 0; i_ < 5; ++i_)                                       \
            gload_lds16(hs_ + (size_t)i_ * 16384, halo + i_ * 8192 + tb16);  \
        if (t512 < 384)                                                      \
            gload_lds16(hs_ + (size_t)5 * 16384, halo + 5 * 8192 + tb16);    \
    } while (0)

    // load B tile (tap,h) into bv (single buffer, 32 VGPR)
    #define LOADB(TAP, H) do {                                               \
        const int bo_ = ((TAP) * 2 + (H)) * 32768;                           \
        _Pragma("unroll")                                                    \
        for (int nf = 0; nf < 4; ++nf) {                                     \
            bv[nf][0] = *(const i32x4*)(bptr[nf] + bo_);                     \
            bv[nf][1] = *(const i32x4*)(bptr[nf] + bo_ + 16384);             \
        }                                                                    \
    } while (0)

    // one K-step: kk0 reads+MFMA, kk1 reads+MFMA, then prefetch next B
    #define STEP(TAP, LB_TAP, LB_H, DO_LB) do {                              \
        const int toff_ = ((TAP) / 3) * W_IN + ((TAP) % 3);                  \
        i32x4 av_[4];                                                        \
        _Pragma("unroll")                                                    \
        for (int kk = 0; kk < 2; ++kk) {                                     \
            _Pragma("unroll")                                                \
            for (int mf = 0; mf < 4; ++mf) {                                 \
                const int row_ = drow[mf] + toff_;                           \
                const unsigned off_ = ((unsigned)row_ << 7) +                \
                    (((unsigned)(kk << 6) + g16) ^ ((unsigned)(row_ & 7) << 4)); \
                av_[mf] = *(const i32x4*)(halo + off_);                      \
            }                                                                \
            __builtin_amdgcn_s_setprio(1);                                   \
            _Pragma("unroll")                                                \
            for (int mf = 0; mf < 4; ++mf)                                   \
                _Pragma("unroll")                                            \
                for (int nf = 0; nf < 4; ++nf)                               \
                    acc[mf][nf] = __builtin_amdgcn_mfma_i32_16x16x64_i8(     \
                        av_[mf], bv[nf][kk], acc[mf][nf], 0, 0, 0);          \
            __builtin_amdgcn_s_setprio(0);                                   \
        }                                                                    \
        if (DO_LB) LOADB(LB_TAP, LB_H);                                      \
    } while (0)

    i32x4 bv[4][2];

    // ---- prologue: halo(half 0) + B(tap0,h0) ----
    STAGE_HALO(0);
    LOADB(0, 0);
    asm volatile("s_waitcnt vmcnt(0)" ::: "memory");   // halo + bv resident
    __builtin_amdgcn_s_barrier();

    // ---- half 0: taps 0..8, barrier-free; prefetch next B after use ----
    #pragma unroll
    for (int t = 0; t < 8; ++t) STEP(t, t + 1, 0, 1);
    STEP(8, 0, 1, 1);                                  // prefetch B(0, half1)

    // ---- halo restage (the only barriers in the kernel) ----
    __builtin_amdgcn_s_barrier();                      // all half-0 reads done
    STAGE_HALO(1);
    asm volatile("s_waitcnt vmcnt(0)" ::: "memory");
    __builtin_amdgcn_s_barrier();

    // ---- half 1: taps 0..8 ----
    #pragma unroll
    for (int t = 0; t < 8; ++t) STEP(t, t + 1, 1, 1);
    STEP(8, 0, 0, 0);

    // ---- epilogue: C/D col=lane&15, row=(lane>>4)*4+reg; float4 stores ----
    const int c16 = l & 15;
    const int p4  = (l >> 4) << 2;
    #pragma unroll
    for (int mf = 0; mf < 4; ++mf) {
        const int m   = mb * BM + wr * 64 + mf * 16 + p4;
        const int n   = m / HW_OUT;
        const int rem = m - n * HW_OUT;
        float* ob = out + (size_t)n * CHW_OUT + rem;
        #pragma unroll
        for (int nf = 0; nf < 4; ++nf) {
            const int ch = wc * 64 + nf * 16 + c16;
            f32x4 v;
            #pragma unroll
            for (int j = 0; j < 4; ++j) v[j] = (float)acc[mf][nf][j];
            *(f32x4*)(ob + (size_t)ch * HW_OUT) = v;
        }
    }
    #undef STEP
    #undef LOADB
    #undef STAGE_HALO
}

// -------- fallback (only if ws too small): naive direct conv, exact --------
__global__ __launch_bounds__(256) void conv_naive(const int* __restrict__ x,
                                                  const float* __restrict__ w,
                                                  float* __restrict__ out) {
    int idx = blockIdx.x * 256 + threadIdx.x;
    if (idx >= N_IMG * K_OUT * HW_OUT) return;
    const int wo = idx % W_OUT;
    int tmp = idx / W_OUT;
    const int ho = tmp % H_OUT; tmp /= H_OUT;
    const int k = tmp % K_OUT;
    const int n = tmp / K_OUT;
    float acc = 0.f;
    for (int c = 0; c < C_IN; ++c) {
        const int* xp = x + ((size_t)((n * C_IN + c) * H_IN + ho)) * W_IN + wo;
        const float* wp = w + ((size_t)(k * C_IN + c)) * 9;
        #pragma unroll
        for (int r = 0; r < 3; ++r)
            #pragma unroll
            for (int s = 0; s < 3; ++s) {
                int xv = xp[r * W_IN + s];
                xv = xv < 0 ? 0 : (xv > 7 ? 7 : xv);
                acc += (float)xv * (float)(int)wp[r * 3 + s];
            }
    }
    out[idx] = acc;
}

extern "C" void kernel_launch(void* const* d_in, const int* in_sizes, int n_in,
                              void* d_out, int out_size, void* d_ws, size_t ws_size,
                              hipStream_t stream) {
    const int*   x = (const int*)d_in[0];
    const float* w = (const float*)d_in[1];
    float* out = (float*)d_out;

    const size_t need = XT_BYTES + WT_BYTES;   // ~26.3 MB (halo OOB stays inside)
    if (ws_size >= need) {
        unsigned char* xt = (unsigned char*)d_ws;
        unsigned char* wt = (unsigned char*)((char*)d_ws + XT_BYTES);
        hipLaunchKernelGGL(xform, dim3(N_IMG * H_IN + K_OUT), dim3(256), 0, stream,
                           x, w, xt, wt);
        hipLaunchKernelGGL(conv_mfma, dim3(M_PIX / BM), dim3(512), 0, stream,
                           xt, wt, out);
    } else {
        const int total = N_IMG * K_OUT * HW_OUT;
        hipLaunchKernelGGL(conv_naive, dim3((total + 255) / 256), dim3(256), 0, stream, x, w, out);
    }
}

// Round 12
// 131.236 us; speedup vs baseline: 1.4674x; 1.4674x over previous
//
#include <hip/hip_runtime.h>
#include <stdint.h>

typedef int i32x4 __attribute__((ext_vector_type(4)));
typedef float f32x4 __attribute__((ext_vector_type(4)));

#define N_IMG 32
#define C_IN 256
#define H_IN 56
#define W_IN 56
#define K_OUT 256
#define H_OUT 54
#define W_OUT 54
#define HW_OUT 2916          // 54*54
#define M_PIX 93312          // 32*2916 = 128 * 729
#define CHW_OUT 746496       // 256*2916

#define BM 128               // pixel rows per block; BN=128 -> grid 729*2
#define HALO_ROWS 368        // max needed row = 359 (245 drow + 114 tap)

#define XT_BYTES ((size_t)N_IMG * H_IN * W_IN * C_IN)   // 25,690,112 (i8 NHWC)
#define WT_BYTES ((size_t)9 * K_OUT * C_IN)             // 589,824

// -------- transforms --------
// xt: NCHW i32 -> NHWC i8 (clip 0..7)
// wt: OIHW f32 -> [tap][h][kk][o][g]x16B: one B-fragment = wave-contiguous 1KB.
//     (tap,h) stride 32768, kk stride 16384, o stride 64, g stride 16.
__global__ __launch_bounds__(256) void xform(const int* __restrict__ x,
                                             const float* __restrict__ w,
                                             unsigned char* __restrict__ xt,
                                             unsigned char* __restrict__ wt) {
    const int bid = blockIdx.x;
    if (bid < N_IMG * H_IN) {
        const int n = bid / H_IN;
        const int h = bid % H_IN;
        const int c = threadIdx.x;
        const int* src = x + ((size_t)((n * C_IN + c) * H_IN + h)) * W_IN;
        unsigned char* dst = xt + ((size_t)(n * H_IN + h) * W_IN) * C_IN + c;
        #pragma unroll
        for (int w0 = 0; w0 < W_IN; w0 += 4) {
            int4 v = *(const int4*)(src + w0);
            int a[4] = {v.x, v.y, v.z, v.w};
            #pragma unroll
            for (int j = 0; j < 4; ++j) {
                int q = a[j] < 0 ? 0 : (a[j] > 7 ? 7 : a[j]);
                dst[(size_t)(w0 + j) * C_IN] = (unsigned char)q;
            }
        }
    } else {
        const int o = bid - N_IMG * H_IN;     // out-channel
        const int c = threadIdx.x;            // in-channel
        const float* src = w + ((size_t)o * C_IN + c) * 9;
        const int h  = c >> 7;                // 128-half
        const int kk = (c >> 6) & 1;          // 64 within half
        const int g  = (c >> 4) & 3;          // 16-chunk within 64
        const int b  = c & 15;                // byte within 16
        #pragma unroll
        for (int rs = 0; rs < 9; ++rs) {
            int iv = (int)src[rs];   // truncation == astype(int32); values 0..6
            wt[(size_t)((rs * 2 + h) * 2 + kk) * 16384 + o * 64 + g * 16 + b]
                = (unsigned char)iv;
        }
    }
}

// -------- async global->LDS (width 16) --------
__device__ __forceinline__ void gload_lds16(const void* g, void* l) {
    __builtin_amdgcn_global_load_lds(
        (const __attribute__((address_space(1))) uint32_t*)g,
        (__attribute__((address_space(3))) uint32_t*)l,
        16, 0, 0);
}

// -------- main conv (i8): 256-thr blocks for cross-block phase diversity ------
// Block = 4 waves (2M x 2N), per-wave 64x64, acc[4][4] = 64 AGPR.
// A: halo LDS 368x128B (47KB) staged once per ch-half; B: global->reg.
// ~144 unified regs -> 3 blocks/CU co-resident, mutually out of phase ->
// MFMA / LDS-read / L2-load pipes overlap across blocks (m114 mechanism).
__global__ __launch_bounds__(256, 3) void conv_mfma(const unsigned char* __restrict__ xt,
                                                    const unsigned char* __restrict__ wt,
                                                    float* __restrict__ out) {
    __shared__ __align__(16) unsigned char halo[HALO_ROWS * 128];   // 47104 B

    const int t256 = threadIdx.x;
    const int l    = t256 & 63;
    const int wid  = t256 >> 6;
    const int wr   = wid >> 1;     // 0..1 -> 64-pixel half
    const int wc   = wid & 1;      // 0..1 -> 64-channel half (of this block's 128)
    const int bid  = blockIdx.x;   // 1458
    const int mb   = bid >> 1;     // 729 M-tiles
    const int nb   = bid & 1;      // 2 N-tiles (128 ch each)

    // halo staging: 256 thr x 16B = 4KB round = 32 rows; both-sides swizzle
    const int slot = t256 & 7;
    const int srow = t256 >> 3;                    // 0..31
    const int cs   = ((slot ^ (srow & 7)) << 4);
    const int tb16 = t256 * 16;
    const int sb   = srow * 256 + cs;

    // block-base input pixel
    const int m0  = mb * BM;
    const int n0  = m0 / HW_OUT;
    const int rm0 = m0 - n0 * HW_OUT;
    const int oh0 = rm0 / W_OUT;
    const int ow0 = rm0 - oh0 * W_OUT;
    const int pix0 = n0 * (H_IN * W_IN) + oh0 * W_IN + ow0;

    // per-lane halo row deltas for the 4 M-fragments (exact mapping, max 245)
    const int lrow = l & 15;
    int drow[4];
    #pragma unroll
    for (int mf = 0; mf < 4; ++mf) {
        const int m   = m0 + wr * 64 + mf * 16 + lrow;
        const int n   = m / HW_OUT;
        const int rem = m - n * HW_OUT;
        const int oh  = rem / W_OUT;
        const int ow  = rem - oh * W_OUT;
        drow[mf] = n * (H_IN * W_IN) + oh * W_IN + ow - pix0;
    }

    const unsigned g16 = (unsigned)((l >> 4) << 4);   // 0/16/32/48

    // B fragment base: layout [tap][h][kk][o][g]x16B (R9-verified strides)
    const char* wb = (const char*)wt;
    const char* bptr[4];
    #pragma unroll
    for (int nf = 0; nf < 4; ++nf)
        bptr[nf] = wb + (nb * 128 + wc * 64 + nf * 16 + lrow) * 64 + (l >> 4) * 16;

    i32x4 acc[4][4];
    #pragma unroll
    for (int i = 0; i < 4; ++i)
        #pragma unroll
        for (int j = 0; j < 4; ++j)
            acc[i][j] = (i32x4){0, 0, 0, 0};

    const char* xb = (const char*)xt;

    // halo: 11 full 4KB rounds (352 rows) + partial (rows 352..367, t<128)
    #define STAGE_HALO(H) do {                                               \
        const char* hs_ = xb + (size_t)pix0 * 256 + (H) * 128 + sb;          \
        _Pragma("unroll")                                                    \
        for (int i_ = 0; i_ < 11; ++i_)                                      \
            gload_lds16(hs_ + (size_t)i_ * 8192, halo + i_ * 4096 + tb16);   \
        if (t256 < 128)                                                      \
            gload_lds16(hs_ + (size_t)11 * 8192, halo + 11 * 4096 + tb16);   \
    } while (0)

    // load B tile (tap,h) into bv (single buffer, 32 VGPR)
    #define LOADB(TAP, H) do {                                               \
        const int bo_ = ((TAP) * 2 + (H)) * 32768;                           \
        _Pragma("unroll")                                                    \
        for (int nf = 0; nf < 4; ++nf) {                                     \
            bv[nf][0] = *(const i32x4*)(bptr[nf] + bo_);                     \
            bv[nf][1] = *(const i32x4*)(bptr[nf] + bo_ + 16384);             \
        }                                                                    \
    } while (0)

    // one K-step: kk0 reads+MFMA, kk1 reads+MFMA, then prefetch next B
    #define STEP(TAP, LB_TAP, LB_H, DO_LB) do {                              \
        const int toff_ = ((TAP) / 3) * W_IN + ((TAP) % 3);                  \
        i32x4 av_[4];                                                        \
        _Pragma("unroll")                                                    \
        for (int kk = 0; kk < 2; ++kk) {                                     \
            _Pragma("unroll")                                                \
            for (int mf = 0; mf < 4; ++mf) {                                 \
                const int row_ = drow[mf] + toff_;                           \
                const unsigned off_ = ((unsigned)row_ << 7) +                \
                    (((unsigned)(kk << 6) + g16) ^ ((unsigned)(row_ & 7) << 4)); \
                av_[mf] = *(const i32x4*)(halo + off_);                      \
            }                                                                \
            __builtin_amdgcn_s_setprio(1);                                   \
            _Pragma("unroll")                                                \
            for (int mf = 0; mf < 4; ++mf)                                   \
                _Pragma("unroll")                                            \
                for (int nf = 0; nf < 4; ++nf)                               \
                    acc[mf][nf] = __builtin_amdgcn_mfma_i32_16x16x64_i8(     \
                        av_[mf], bv[nf][kk], acc[mf][nf], 0, 0, 0);          \
            __builtin_amdgcn_s_setprio(0);                                   \
        }                                                                    \
        if (DO_LB) LOADB(LB_TAP, LB_H);                                      \
    } while (0)

    i32x4 bv[4][2];

    // ---- prologue: halo(half 0) + B(tap0,h0) ----
    STAGE_HALO(0);
    LOADB(0, 0);
    asm volatile("s_waitcnt vmcnt(0)" ::: "memory");   // halo + bv resident
    __builtin_amdgcn_s_barrier();

    // ---- half 0: taps 0..8, barrier-free; prefetch next B after use ----
    #pragma unroll
    for (int t = 0; t < 8; ++t) STEP(t, t + 1, 0, 1);
    STEP(8, 0, 1, 1);                                  // prefetch B(0, half1)

    // ---- halo restage (the only barriers in the kernel) ----
    __builtin_amdgcn_s_barrier();                      // all half-0 reads done
    STAGE_HALO(1);
    asm volatile("s_waitcnt vmcnt(0)" ::: "memory");
    __builtin_amdgcn_s_barrier();

    // ---- half 1: taps 0..8 ----
    #pragma unroll
    for (int t = 0; t < 8; ++t) STEP(t, t + 1, 1, 1);
    STEP(8, 0, 0, 0);

    // ---- epilogue: C/D col=lane&15, row=(lane>>4)*4+reg; float4 stores ----
    const int c16 = l & 15;
    const int p4  = (l >> 4) << 2;
    #pragma unroll
    for (int mf = 0; mf < 4; ++mf) {
        const int m   = mb * BM + wr * 64 + mf * 16 + p4;
        const int n   = m / HW_OUT;
        const int rem = m - n * HW_OUT;
        float* ob = out + (size_t)n * CHW_OUT + rem;
        #pragma unroll
        for (int nf = 0; nf < 4; ++nf) {
            const int ch = nb * 128 + wc * 64 + nf * 16 + c16;
            f32x4 v;
            #pragma unroll
            for (int j = 0; j < 4; ++j) v[j] = (float)acc[mf][nf][j];
            *(f32x4*)(ob + (size_t)ch * HW_OUT) = v;
        }
    }
    #undef STEP
    #undef LOADB
    #undef STAGE_HALO
}

// -------- fallback (only if ws too small): naive direct conv, exact --------
__global__ __launch_bounds__(256) void conv_naive(const int* __restrict__ x,
                                                  const float* __restrict__ w,
                                                  float* __restrict__ out) {
    int idx = blockIdx.x * 256 + threadIdx.x;
    if (idx >= N_IMG * K_OUT * HW_OUT) return;
    const int wo = idx % W_OUT;
    int tmp = idx / W_OUT;
    const int ho = tmp % H_OUT; tmp /= H_OUT;
    const int k = tmp % K_OUT;
    const int n = tmp / K_OUT;
    float acc = 0.f;
    for (int c = 0; c < C_IN; ++c) {
        const int* xp = x + ((size_t)((n * C_IN + c) * H_IN + ho)) * W_IN + wo;
        const float* wp = w + ((size_t)(k * C_IN + c)) * 9;
        #pragma unroll
        for (int r = 0; r < 3; ++r)
            #pragma unroll
            for (int s = 0; s < 3; ++s) {
                int xv = xp[r * W_IN + s];
                xv = xv < 0 ? 0 : (xv > 7 ? 7 : xv);
                acc += (float)xv * (float)(int)wp[r * 3 + s];
            }
    }
    out[idx] = acc;
}

extern "C" void kernel_launch(void* const* d_in, const int* in_sizes, int n_in,
                              void* d_out, int out_size, void* d_ws, size_t ws_size,
                              hipStream_t stream) {
    const int*   x = (const int*)d_in[0];
    const float* w = (const float*)d_in[1];
    float* out = (float*)d_out;

    const size_t need = XT_BYTES + WT_BYTES;   // ~26.3 MB (halo OOB stays inside)
    if (ws_size >= need) {
        unsigned char* xt = (unsigned char*)d_ws;
        unsigned char* wt = (unsigned char*)((char*)d_ws + XT_BYTES);
        hipLaunchKernelGGL(xform, dim3(N_IMG * H_IN + K_OUT), dim3(256), 0, stream,
                           x, w, xt, wt);
        hipLaunchKernelGGL(conv_mfma, dim3((M_PIX / BM) * 2), dim3(256), 0, stream,
                           xt, wt, out);
    } else {
        const int total = N_IMG * K_OUT * HW_OUT;
        hipLaunchKernelGGL(conv_naive, dim3((total + 255) / 256), dim3(256), 0, stream, x, w, out);
    }
}